// Round 9
// baseline (129.671 us; speedup 1.0000x reference)
//
#include <hip/hip_runtime.h>

// Problem constants (B=8, K=32 -> N=256 patches; C=3; H=W=128)
#define HH 128
#define WW 128
#define HW (HH * WW)

// ---------------------------------------------------------------------------
// Target: bit-match the jax-CPU (XLA f32) reference's nearest decisions.
//  - trig: glibc cosf/sinf ~ correctly-rounded f32 (compute f64, round once)
//  - rotation einsum: XLA dot-reduction FMA lowering, j ascending, acc seed 0:
//      gx = fma(-s, y, fl(c*x)),  gy = fma(c, y, fl(s*x))
//  - scale einsum reduces to fl(sc*x) (other terms are exact zeros)
//  - pixel-coord chain: only fl(g+1) rounds; *128, -1, /2 exact (proven)
//  - round half-to-even (rintf), clip+int-cast, OOB->0
// Flip folds into pass-1 exactly: xs[W-1-w] == -xs[w] bitwise (dyadics).
// ---------------------------------------------------------------------------
__global__ void pa_param_kernel(const float* __restrict__ angles,
                                const int* __restrict__ flip_h,
                                const int* __restrict__ flip_v,
                                const float* __restrict__ scales,
                                float* __restrict__ params, int N) {
    int n = blockIdx.x * blockDim.x + threadIdx.x;
    if (n >= N) return;
    double a = (double)angles[n];
    params[n * 8 + 0] = (float)cos(a);   // correctly-rounded f32 cos
    params[n * 8 + 1] = (float)sin(a);   // correctly-rounded f32 sin
    params[n * 8 + 2] = flip_h[n] ? -1.0f : 1.0f;
    params[n * 8 + 3] = flip_v[n] ? -1.0f : 1.0f;
    params[n * 8 + 4] = scales[n];
}

// xs[i] = (2*i+1)/128 - 1  (exact dyadic in f32)
__device__ __forceinline__ float norm_coord(int i) {
    return __fsub_rn(__fmul_rn((float)(2 * i + 1), 0.0078125f), 1.0f);
}

// ix = ((g + 1)*128 - 1) / 2 with f32 rounding at each step
__device__ __forceinline__ float pix_coord(float g) {
    float t = __fadd_rn(g, 1.0f);
    t = __fmul_rn(t, 128.0f);
    t = __fsub_rn(t, 1.0f);
    return __fmul_rn(t, 0.5f);
}

// XLA dot-reduction FMA lowering of the rotation grid (j ascending, seed 0):
//   acc = fma(c, x, 0) = fl(c*x);  acc = fma(-s, y, acc);  acc = fma(0,1,acc)
__device__ __forceinline__ float rot_gx(float c, float s, float x, float y) {
    return __fmaf_rn(-s, y, __fmul_rn(c, x));
}
__device__ __forceinline__ float rot_gy(float c, float s, float x, float y) {
    return __fmaf_rn(c, y, __fmul_rn(s, x));
}

__device__ __forceinline__ float corner_val(const float* __restrict__ img,
                                            int x, int y, float w) {
    if ((unsigned)x < (unsigned)WW && (unsigned)y < (unsigned)HH)
        return __fmul_rn(img[y * WW + x], w);
    return 0.0f;
}

__device__ __forceinline__ float bilinear_sample(const float* __restrict__ img,
                                                 float ix, float iy) {
    float x0f = floorf(ix), y0f = floorf(iy);
    float wx1 = __fsub_rn(ix, x0f), wy1 = __fsub_rn(iy, y0f);
    float wx0 = __fsub_rn(1.0f, wx1), wy0 = __fsub_rn(1.0f, wy1);
    int x0 = (int)x0f, y0 = (int)y0f;
    float acc;
    acc = corner_val(img, x0, y0, __fmul_rn(wx0, wy0));
    acc = __fadd_rn(acc, corner_val(img, x0 + 1, y0,     __fmul_rn(wx1, wy0)));
    acc = __fadd_rn(acc, corner_val(img, x0,     y0 + 1, __fmul_rn(wx0, wy1)));
    acc = __fadd_rn(acc, corner_val(img, x0 + 1, y0 + 1, __fmul_rn(wx1, wy1)));
    return acc;
}

// ---------------------------------------------------------------------------
// Patches pass 1: rotation bilinear with flip folded in (negated coord).
// ---------------------------------------------------------------------------
__global__ void __launch_bounds__(256)
pa_rot_patches(const float* __restrict__ patches,
               const float* __restrict__ params,
               float* __restrict__ ws_p) {
    int idx = blockIdx.x * 256 + threadIdx.x;
    int w  = idx & (WW - 1);
    int h  = (idx >> 7) & (HH - 1);
    int n3 = idx >> 14;                 // n*3 + ch
    int n  = n3 / 3;

    const float* pr = params + n * 8;
    float c = pr[0], s = pr[1], fsx = pr[2], fsy = pr[3];

    float x = __fmul_rn(fsx, norm_coord(w));   // exact sign flip of dyadic
    float y = __fmul_rn(fsy, norm_coord(h));
    float gx = rot_gx(c, s, x, y);
    float gy = rot_gy(c, s, x, y);

    const float* img = patches + (size_t)n3 * HW;
    ws_p[(size_t)n3 * HW + h * WW + w] =
        bilinear_sample(img, pix_coord(gx), pix_coord(gy));
}

// ---------------------------------------------------------------------------
// Patches pass 2: scale bilinear from ws_p -> out_p.
// ---------------------------------------------------------------------------
__global__ void __launch_bounds__(256)
pa_scale_patches(const float* __restrict__ ws_p,
                 const float* __restrict__ params,
                 float* __restrict__ out_p) {
    int idx = blockIdx.x * 256 + threadIdx.x;
    int w  = idx & (WW - 1);
    int h  = (idx >> 7) & (HH - 1);
    int n3 = idx >> 14;
    int n  = n3 / 3;

    float sc = params[n * 8 + 4];
    float gx = __fmul_rn(sc, norm_coord(w));
    float gy = __fmul_rn(sc, norm_coord(h));

    const float* img = ws_p + (size_t)n3 * HW;
    out_p[(size_t)n3 * HW + h * WW + w] =
        bilinear_sample(img, pix_coord(gx), pix_coord(gy));
}

// ---------------------------------------------------------------------------
// Labels: FUSED nearest-of-nearest = pure index composition, no workspace.
// ---------------------------------------------------------------------------
__global__ void __launch_bounds__(256)
pa_labels_fused(const float* __restrict__ labels,
                const float* __restrict__ params,
                float* __restrict__ out_l) {
    int idx = blockIdx.x * 256 + threadIdx.x;
    int w = idx & (WW - 1);
    int h = (idx >> 7) & (HH - 1);
    int n = idx >> 14;

    const float* pr = params + n * 8;
    float c = pr[0], s = pr[1], fsx = pr[2], fsy = pr[3], sc = pr[4];

    // pass 2 (scale) nearest index
    float ix2 = pix_coord(__fmul_rn(sc, norm_coord(w)));
    float iy2 = pix_coord(__fmul_rn(sc, norm_coord(h)));
    float xr2 = rintf(ix2), yr2 = rintf(iy2);
    float outv = 0.0f;
    if (xr2 >= 0.0f && xr2 <= 127.0f && yr2 >= 0.0f && yr2 <= 127.0f) {
        int w2 = (int)xr2, h2 = (int)yr2;
        // pass 1 (rotation+flip) nearest index evaluated at (h2, w2)
        float x = __fmul_rn(fsx, norm_coord(w2));
        float y = __fmul_rn(fsy, norm_coord(h2));
        float gx = rot_gx(c, s, x, y);
        float gy = rot_gy(c, s, x, y);
        float ix1 = pix_coord(gx), iy1 = pix_coord(gy);
        float xr1 = rintf(ix1), yr1 = rintf(iy1);
        if (xr1 >= 0.0f && xr1 <= 127.0f && yr1 >= 0.0f && yr1 <= 127.0f) {
            outv = labels[(size_t)n * HW + (int)yr1 * WW + (int)xr1];
        }
    }
    out_l[(size_t)n * HW + h * WW + w] = outv;
}

extern "C" void kernel_launch(void* const* d_in, const int* in_sizes, int n_in,
                              void* d_out, int out_size, void* d_ws, size_t ws_size,
                              hipStream_t stream) {
    const float* patches = (const float*)d_in[0];
    const float* labels  = (const float*)d_in[1];
    const float* angles  = (const float*)d_in[2];
    const int*   flip_h  = (const int*)d_in[3];
    const int*   flip_v  = (const int*)d_in[4];
    const float* scales  = (const float*)d_in[5];

    const int N = in_sizes[2];            // B*K = 256
    float* out   = (float*)d_out;
    float* out_p = out;                   // N*3*H*W
    float* out_l = out + (size_t)N * 3 * HW;

    // ws layout: params (8 KB) + ws_p (50.33 MB). No ws_l (fused labels).
    float* params = (float*)d_ws;
    float* ws_p   = params + (size_t)N * 8;

    pa_param_kernel<<<(N + 255) / 256, 256, 0, stream>>>(angles, flip_h, flip_v,
                                                         scales, params, N);

    int pblocks = N * 3 * HW / 256;       // 49,152
    int lblocks = N * HW / 256;           // 16,384
    pa_rot_patches<<<pblocks, 256, 0, stream>>>(patches, params, ws_p);
    pa_scale_patches<<<pblocks, 256, 0, stream>>>(ws_p, params, out_p);
    pa_labels_fused<<<lblocks, 256, 0, stream>>>(labels, params, out_l);
}

// Round 10
// 96.179 us; speedup vs baseline: 1.3482x; 1.3482x over previous
//
#include <hip/hip_runtime.h>

// Problem constants (B=8, K=32 -> N=256 patches; C=3; H=W=128)
#define HH 128
#define WW 128
#define HW (HH * WW)

// ---------------------------------------------------------------------------
// Verified-correct arithmetic (Round 9, passed):
//  - trig: correctly-rounded f32 cos/sin (f64 libm, rounded once)
//  - rotation einsum: XLA dot-reduction FMA lowering:
//      gx = fma(-s, y, fl(c*x)),  gy = fma(c, y, fl(s*x))
//  - scale einsum: fl(sc*x)
//  - pix chain: fl(g+1)*128-1)*0.5 stepwise; rintf half-even; OOB->0
//  - flip folded into pass-1 coords: xs[W-1-w] == -xs[w] bitwise (dyadics)
// This round: SAME arithmetic, fused structure (LDS slice intermediate).
// ---------------------------------------------------------------------------

// xs[i] = (2*i+1)/128 - 1  (exact dyadic in f32)
__device__ __forceinline__ float norm_coord(int i) {
    return __fsub_rn(__fmul_rn((float)(2 * i + 1), 0.0078125f), 1.0f);
}

// ix = ((g + 1)*128 - 1) / 2 with f32 rounding at each step
__device__ __forceinline__ float pix_coord(float g) {
    float t = __fadd_rn(g, 1.0f);
    t = __fmul_rn(t, 128.0f);
    t = __fsub_rn(t, 1.0f);
    return __fmul_rn(t, 0.5f);
}

// XLA dot-reduction FMA lowering of the rotation grid
__device__ __forceinline__ float rot_gx(float c, float s, float x, float y) {
    return __fmaf_rn(-s, y, __fmul_rn(c, x));
}
__device__ __forceinline__ float rot_gy(float c, float s, float x, float y) {
    return __fmaf_rn(c, y, __fmul_rn(s, x));
}

__device__ __forceinline__ float corner_g(const float* __restrict__ img,
                                          int x, int y, float w) {
    if ((unsigned)x < (unsigned)WW && (unsigned)y < (unsigned)HH)
        return __fmul_rn(img[y * WW + x], w);
    return 0.0f;
}

__device__ __forceinline__ float bilinear_g(const float* __restrict__ img,
                                            float ix, float iy) {
    float x0f = floorf(ix), y0f = floorf(iy);
    float wx1 = __fsub_rn(ix, x0f), wy1 = __fsub_rn(iy, y0f);
    float wx0 = __fsub_rn(1.0f, wx1), wy0 = __fsub_rn(1.0f, wy1);
    int x0 = (int)x0f, y0 = (int)y0f;
    float acc;
    acc = corner_g(img, x0, y0, __fmul_rn(wx0, wy0));
    acc = __fadd_rn(acc, corner_g(img, x0 + 1, y0,     __fmul_rn(wx1, wy0)));
    acc = __fadd_rn(acc, corner_g(img, x0,     y0 + 1, __fmul_rn(wx0, wy1)));
    acc = __fadd_rn(acc, corner_g(img, x0 + 1, y0 + 1, __fmul_rn(wx1, wy1)));
    return acc;
}

__device__ __forceinline__ float corner_l(const float* t, int x, int y, float w) {
    if ((unsigned)x < (unsigned)WW && (unsigned)y < (unsigned)HH)
        return __fmul_rn(t[y * WW + x], w);
    return 0.0f;
}

__device__ __forceinline__ float bilinear_l(const float* t, float ix, float iy) {
    float x0f = floorf(ix), y0f = floorf(iy);
    float wx1 = __fsub_rn(ix, x0f), wy1 = __fsub_rn(iy, y0f);
    float wx0 = __fsub_rn(1.0f, wx1), wy0 = __fsub_rn(1.0f, wy1);
    int x0 = (int)x0f, y0 = (int)y0f;
    float acc;
    acc = corner_l(t, x0, y0, __fmul_rn(wx0, wy0));
    acc = __fadd_rn(acc, corner_l(t, x0 + 1, y0,     __fmul_rn(wx1, wy0)));
    acc = __fadd_rn(acc, corner_l(t, x0,     y0 + 1, __fmul_rn(wx0, wy1)));
    acc = __fadd_rn(acc, corner_l(t, x0 + 1, y0 + 1, __fmul_rn(wx1, wy1)));
    return acc;
}

// ---------------------------------------------------------------------------
// One workgroup per slice. Slices [0, 3N): patch channel slices — pass 1
// (rot+flip) into a 64 KB LDS tile, sync, pass 2 (scale) from LDS to out.
// Slices [3N, 4N): label slices — fused nearest-of-nearest index composition
// straight from global (no LDS needed). All 512 threads of a block take the
// same branch (no divergence). Params computed per-block (thread 0).
// ---------------------------------------------------------------------------
__global__ void __launch_bounds__(512)
pa_fused(const float* __restrict__ patches,
         const float* __restrict__ labels,
         const float* __restrict__ angles,
         const int* __restrict__ flip_h,
         const int* __restrict__ flip_v,
         const float* __restrict__ scales,
         float* __restrict__ out_p,
         float* __restrict__ out_l,
         int N3) {
    __shared__ float tile[HW];       // 64 KB: pass-1 intermediate (f32 == ws_p)
    __shared__ float prm[5];
    int slice = blockIdx.x;
    int tid = threadIdx.x;
    bool is_patch = slice < N3;
    int n = is_patch ? (slice / 3) : (slice - N3);

    if (tid == 0) {
        double a = (double)angles[n];
        prm[0] = (float)cos(a);      // correctly-rounded f32
        prm[1] = (float)sin(a);
        prm[2] = flip_h[n] ? -1.0f : 1.0f;
        prm[3] = flip_v[n] ? -1.0f : 1.0f;
        prm[4] = scales[n];
    }
    __syncthreads();
    float c = prm[0], s = prm[1], fsx = prm[2], fsy = prm[3], sc = prm[4];

    if (is_patch) {
        const float* img = patches + (size_t)slice * HW;
        #pragma unroll
        for (int i = 0; i < HW / 512; ++i) {
            int p = i * 512 + tid;
            int w = p & (WW - 1), h = p >> 7;
            float x = __fmul_rn(fsx, norm_coord(w));   // exact sign flip
            float y = __fmul_rn(fsy, norm_coord(h));
            float gx = rot_gx(c, s, x, y);
            float gy = rot_gy(c, s, x, y);
            tile[p] = bilinear_g(img, pix_coord(gx), pix_coord(gy));
        }
        __syncthreads();
        float* op = out_p + (size_t)slice * HW;
        #pragma unroll
        for (int i = 0; i < HW / 512; ++i) {
            int p = i * 512 + tid;
            int w = p & (WW - 1), h = p >> 7;
            float gx = __fmul_rn(sc, norm_coord(w));
            float gy = __fmul_rn(sc, norm_coord(h));
            op[p] = bilinear_l(tile, pix_coord(gx), pix_coord(gy));
        }
    } else {
        const float* lab = labels + (size_t)n * HW;
        float* ol = out_l + (size_t)n * HW;
        #pragma unroll
        for (int i = 0; i < HW / 512; ++i) {
            int p = i * 512 + tid;
            int w = p & (WW - 1), h = p >> 7;
            // pass 2 (scale) nearest index
            float ix2 = pix_coord(__fmul_rn(sc, norm_coord(w)));
            float iy2 = pix_coord(__fmul_rn(sc, norm_coord(h)));
            float xr2 = rintf(ix2), yr2 = rintf(iy2);
            float outv = 0.0f;
            if (xr2 >= 0.0f && xr2 <= 127.0f && yr2 >= 0.0f && yr2 <= 127.0f) {
                int w2 = (int)xr2, h2 = (int)yr2;
                // pass 1 (rot+flip) nearest index evaluated at (h2, w2)
                float x = __fmul_rn(fsx, norm_coord(w2));
                float y = __fmul_rn(fsy, norm_coord(h2));
                float gx = rot_gx(c, s, x, y);
                float gy = rot_gy(c, s, x, y);
                float xr1 = rintf(pix_coord(gx)), yr1 = rintf(pix_coord(gy));
                if (xr1 >= 0.0f && xr1 <= 127.0f &&
                    yr1 >= 0.0f && yr1 <= 127.0f) {
                    outv = lab[(int)yr1 * WW + (int)xr1];
                }
            }
            ol[p] = outv;
        }
    }
}

extern "C" void kernel_launch(void* const* d_in, const int* in_sizes, int n_in,
                              void* d_out, int out_size, void* d_ws, size_t ws_size,
                              hipStream_t stream) {
    const float* patches = (const float*)d_in[0];
    const float* labels  = (const float*)d_in[1];
    const float* angles  = (const float*)d_in[2];
    const int*   flip_h  = (const int*)d_in[3];
    const int*   flip_v  = (const int*)d_in[4];
    const float* scales  = (const float*)d_in[5];

    const int N = in_sizes[2];            // B*K = 256
    float* out   = (float*)d_out;
    float* out_p = out;                   // N*3*H*W
    float* out_l = out + (size_t)N * 3 * HW;

    int grid = N * 4;                     // 768 patch slices + 256 label slices
    pa_fused<<<grid, 512, 0, stream>>>(patches, labels, angles, flip_h, flip_v,
                                       scales, out_p, out_l, N * 3);
}

// Round 11
// 81.458 us; speedup vs baseline: 1.5919x; 1.1807x over previous
//
#include <hip/hip_runtime.h>

// Problem constants (B=8, K=32 -> N=256 patches; C=3; H=W=128)
#define HH 128
#define WW 128
#define HW (HH * WW)

// ---------------------------------------------------------------------------
// Verified-correct arithmetic (Round 9/10, passed):
//  - trig: correctly-rounded f32 cos/sin (f64 libm, rounded once)
//  - rotation einsum: XLA FMA lowering: gx=fma(-s,y,fl(c*x)), gy=fma(c,y,fl(s*x))
//  - scale einsum: fl(sc*x); pix chain stepwise; rintf half-even; OOB->0
//  - flip folded into pass-1 coords (exact dyadic sign flip)
// This round: SAME arithmetic; 1024-thr blocks (100% occ cap) + branchless
// clamped gathers (ILP). OOB corner = fl(0*w) = +0 == branch's 0.0f: bit-same.
// ---------------------------------------------------------------------------

__device__ __forceinline__ float norm_coord(int i) {
    return __fsub_rn(__fmul_rn((float)(2 * i + 1), 0.0078125f), 1.0f);
}

__device__ __forceinline__ float pix_coord(float g) {
    float t = __fadd_rn(g, 1.0f);
    t = __fmul_rn(t, 128.0f);
    t = __fsub_rn(t, 1.0f);
    return __fmul_rn(t, 0.5f);
}

__device__ __forceinline__ float rot_gx(float c, float s, float x, float y) {
    return __fmaf_rn(-s, y, __fmul_rn(c, x));
}
__device__ __forceinline__ float rot_gy(float c, float s, float x, float y) {
    return __fmaf_rn(c, y, __fmul_rn(s, x));
}

__device__ __forceinline__ int clamp127(int v) {
    return v < 0 ? 0 : (v > 127 ? 127 : v);
}

// Branchless bilinear: 4 unconditional clamped loads (global or LDS),
// value-select for OOB, then the exact R9 accumulation order.
template <typename PtrT>
__device__ __forceinline__ float bilinear_bl(PtrT img, float ix, float iy) {
    float x0f = floorf(ix), y0f = floorf(iy);
    float wx1 = __fsub_rn(ix, x0f), wy1 = __fsub_rn(iy, y0f);
    float wx0 = __fsub_rn(1.0f, wx1), wy0 = __fsub_rn(1.0f, wy1);
    int x0 = (int)x0f, y0 = (int)y0f;
    int x1 = x0 + 1, y1 = y0 + 1;
    bool bx0 = (unsigned)x0 < 128u, bx1 = (unsigned)x1 < 128u;
    bool by0 = (unsigned)y0 < 128u, by1 = (unsigned)y1 < 128u;
    int xc0 = clamp127(x0), xc1 = clamp127(x1);
    int yc0 = clamp127(y0) * WW, yc1 = clamp127(y1) * WW;
    float v00 = img[yc0 + xc0];
    float v10 = img[yc0 + xc1];
    float v01 = img[yc1 + xc0];
    float v11 = img[yc1 + xc1];
    v00 = (bx0 && by0) ? v00 : 0.0f;
    v10 = (bx1 && by0) ? v10 : 0.0f;
    v01 = (bx0 && by1) ? v01 : 0.0f;
    v11 = (bx1 && by1) ? v11 : 0.0f;
    float acc;
    acc = __fmul_rn(v00, __fmul_rn(wx0, wy0));
    acc = __fadd_rn(acc, __fmul_rn(v10, __fmul_rn(wx1, wy0)));
    acc = __fadd_rn(acc, __fmul_rn(v01, __fmul_rn(wx0, wy1)));
    acc = __fadd_rn(acc, __fmul_rn(v11, __fmul_rn(wx1, wy1)));
    return acc;
}

// ---------------------------------------------------------------------------
// Patches: one 1024-thread block per channel slice. Pass 1 (rot+flip) into
// 64 KB LDS tile, sync, pass 2 (scale) from LDS. 2 blocks/CU = 32 waves/CU.
// ---------------------------------------------------------------------------
__global__ void __launch_bounds__(1024, 8)
pa_patches(const float* __restrict__ patches,
           const float* __restrict__ angles,
           const int* __restrict__ flip_h,
           const int* __restrict__ flip_v,
           const float* __restrict__ scales,
           float* __restrict__ out_p) {
    __shared__ float tile[HW];
    __shared__ float prm[5];
    int slice = blockIdx.x;          // n*3 + ch
    int n = slice / 3;
    int tid = threadIdx.x;

    if (tid == 0) {
        double a = (double)angles[n];
        prm[0] = (float)cos(a);      // correctly-rounded f32
        prm[1] = (float)sin(a);
        prm[2] = flip_h[n] ? -1.0f : 1.0f;
        prm[3] = flip_v[n] ? -1.0f : 1.0f;
        prm[4] = scales[n];
    }
    __syncthreads();
    float c = prm[0], s = prm[1], fsx = prm[2], fsy = prm[3], sc = prm[4];

    const float* img = patches + (size_t)slice * HW;
    #pragma unroll 4
    for (int i = 0; i < HW / 1024; ++i) {     // 16 iters
        int p = i * 1024 + tid;
        int w = p & (WW - 1), h = p >> 7;
        float x = __fmul_rn(fsx, norm_coord(w));   // exact sign flip
        float y = __fmul_rn(fsy, norm_coord(h));
        float ix = pix_coord(rot_gx(c, s, x, y));
        float iy = pix_coord(rot_gy(c, s, x, y));
        tile[p] = bilinear_bl(img, ix, iy);
    }
    __syncthreads();
    float* op = out_p + (size_t)slice * HW;
    #pragma unroll 4
    for (int i = 0; i < HW / 1024; ++i) {
        int p = i * 1024 + tid;
        int w = p & (WW - 1), h = p >> 7;
        float ix = pix_coord(__fmul_rn(sc, norm_coord(w)));
        float iy = pix_coord(__fmul_rn(sc, norm_coord(h)));
        op[p] = bilinear_bl((const float*)tile, ix, iy);
    }
}

// ---------------------------------------------------------------------------
// Labels: fused nearest-of-nearest index composition, no LDS.
// ---------------------------------------------------------------------------
__global__ void __launch_bounds__(256)
pa_labels(const float* __restrict__ labels,
          const float* __restrict__ angles,
          const int* __restrict__ flip_h,
          const int* __restrict__ flip_v,
          const float* __restrict__ scales,
          float* __restrict__ out_l) {
    int idx = blockIdx.x * 256 + threadIdx.x;
    int w = idx & (WW - 1);
    int h = (idx >> 7) & (HH - 1);
    int n = idx >> 14;

    double a = (double)angles[n];
    float c = (float)cos(a), s = (float)sin(a);
    float fsx = flip_h[n] ? -1.0f : 1.0f;
    float fsy = flip_v[n] ? -1.0f : 1.0f;
    float sc = scales[n];

    // pass 2 (scale) nearest index
    float ix2 = pix_coord(__fmul_rn(sc, norm_coord(w)));
    float iy2 = pix_coord(__fmul_rn(sc, norm_coord(h)));
    float xr2 = rintf(ix2), yr2 = rintf(iy2);
    float outv = 0.0f;
    if (xr2 >= 0.0f && xr2 <= 127.0f && yr2 >= 0.0f && yr2 <= 127.0f) {
        int w2 = (int)xr2, h2 = (int)yr2;
        // pass 1 (rot+flip) nearest index evaluated at (h2, w2)
        float x = __fmul_rn(fsx, norm_coord(w2));
        float y = __fmul_rn(fsy, norm_coord(h2));
        float xr1 = rintf(pix_coord(rot_gx(c, s, x, y)));
        float yr1 = rintf(pix_coord(rot_gy(c, s, x, y)));
        if (xr1 >= 0.0f && xr1 <= 127.0f && yr1 >= 0.0f && yr1 <= 127.0f) {
            outv = labels[(size_t)n * HW + (int)yr1 * WW + (int)xr1];
        }
    }
    out_l[(size_t)n * HW + h * WW + w] = outv;
}

extern "C" void kernel_launch(void* const* d_in, const int* in_sizes, int n_in,
                              void* d_out, int out_size, void* d_ws, size_t ws_size,
                              hipStream_t stream) {
    const float* patches = (const float*)d_in[0];
    const float* labels  = (const float*)d_in[1];
    const float* angles  = (const float*)d_in[2];
    const int*   flip_h  = (const int*)d_in[3];
    const int*   flip_v  = (const int*)d_in[4];
    const float* scales  = (const float*)d_in[5];

    const int N = in_sizes[2];            // B*K = 256
    float* out   = (float*)d_out;
    float* out_p = out;                   // N*3*H*W
    float* out_l = out + (size_t)N * 3 * HW;

    pa_patches<<<N * 3, 1024, 0, stream>>>(patches, angles, flip_h, flip_v,
                                           scales, out_p);
    pa_labels<<<N * HW / 256, 256, 0, stream>>>(labels, angles, flip_h, flip_v,
                                                scales, out_l);
}

// Round 12
// 70.963 us; speedup vs baseline: 1.8273x; 1.1479x over previous
//
#include <hip/hip_runtime.h>

// Problem constants (B=8, K=32 -> N=256 patches; C=3; H=W=128)
#define HH 128
#define WW 128
#define HW (HH * WW)
#define BAND 16            // output rows per block
#define TROWS 20           // LDS tile rows (max needed: ceil(15*1.1)+2 = 19)

// ---------------------------------------------------------------------------
// Verified-correct arithmetic (R9-R11, passed):
//  - trig: correctly-rounded f32 cos/sin (f64 libm, rounded once)
//  - rotation einsum: XLA FMA lowering: gx=fma(-s,y,fl(c*x)), gy=fma(c,y,fl(s*x))
//  - scale einsum: fl(sc*x); pix chain stepwise; rintf half-even; OOB->0
//  - flip folded into pass-1 coords (exact dyadic sign flip)
//  - branchless clamped gathers: OOB corner = fl(0*w) = +0 == 0.0f, bit-same
// This round: SAME arithmetic; banded LDS tile (scale pass is separable and
// monotone in h: output rows [r0,r0+16) need <=19 intermediate rows).
// ---------------------------------------------------------------------------

__device__ __forceinline__ float norm_coord(int i) {
    return __fsub_rn(__fmul_rn((float)(2 * i + 1), 0.0078125f), 1.0f);
}

__device__ __forceinline__ float pix_coord(float g) {
    float t = __fadd_rn(g, 1.0f);
    t = __fmul_rn(t, 128.0f);
    t = __fsub_rn(t, 1.0f);
    return __fmul_rn(t, 0.5f);
}

__device__ __forceinline__ float rot_gx(float c, float s, float x, float y) {
    return __fmaf_rn(-s, y, __fmul_rn(c, x));
}
__device__ __forceinline__ float rot_gy(float c, float s, float x, float y) {
    return __fmaf_rn(c, y, __fmul_rn(s, x));
}

__device__ __forceinline__ int clamp127(int v) {
    return v < 0 ? 0 : (v > 127 ? 127 : v);
}

// Branchless bilinear from a full 128x128 global slice.
__device__ __forceinline__ float bilinear_g(const float* __restrict__ img,
                                            float ix, float iy) {
    float x0f = floorf(ix), y0f = floorf(iy);
    float wx1 = __fsub_rn(ix, x0f), wy1 = __fsub_rn(iy, y0f);
    float wx0 = __fsub_rn(1.0f, wx1), wy0 = __fsub_rn(1.0f, wy1);
    int x0 = (int)x0f, y0 = (int)y0f;
    int x1 = x0 + 1, y1 = y0 + 1;
    bool bx0 = (unsigned)x0 < 128u, bx1 = (unsigned)x1 < 128u;
    bool by0 = (unsigned)y0 < 128u, by1 = (unsigned)y1 < 128u;
    int xc0 = clamp127(x0), xc1 = clamp127(x1);
    int yc0 = clamp127(y0) * WW, yc1 = clamp127(y1) * WW;
    float v00 = img[yc0 + xc0];
    float v10 = img[yc0 + xc1];
    float v01 = img[yc1 + xc0];
    float v11 = img[yc1 + xc1];
    v00 = (bx0 && by0) ? v00 : 0.0f;
    v10 = (bx1 && by0) ? v10 : 0.0f;
    v01 = (bx0 && by1) ? v01 : 0.0f;
    v11 = (bx1 && by1) ? v11 : 0.0f;
    float acc;
    acc = __fmul_rn(v00, __fmul_rn(wx0, wy0));
    acc = __fadd_rn(acc, __fmul_rn(v10, __fmul_rn(wx1, wy0)));
    acc = __fadd_rn(acc, __fmul_rn(v01, __fmul_rn(wx0, wy1)));
    acc = __fadd_rn(acc, __fmul_rn(v11, __fmul_rn(wx1, wy1)));
    return acc;
}

// Branchless bilinear from the banded LDS tile (rows [lo, lo+nrows)).
// y0/y1 after global clamp are guaranteed within the band (monotone range).
__device__ __forceinline__ float bilinear_band(const float* t, int lo,
                                               float ix, float iy) {
    float x0f = floorf(ix), y0f = floorf(iy);
    float wx1 = __fsub_rn(ix, x0f), wy1 = __fsub_rn(iy, y0f);
    float wx0 = __fsub_rn(1.0f, wx1), wy0 = __fsub_rn(1.0f, wy1);
    int x0 = (int)x0f, y0 = (int)y0f;
    int x1 = x0 + 1, y1 = y0 + 1;
    bool bx0 = (unsigned)x0 < 128u, bx1 = (unsigned)x1 < 128u;
    bool by0 = (unsigned)y0 < 128u, by1 = (unsigned)y1 < 128u;
    int xc0 = clamp127(x0), xc1 = clamp127(x1);
    int t0 = (clamp127(y0) - lo) * WW, t1 = (clamp127(y1) - lo) * WW;
    float v00 = t[t0 + xc0];
    float v10 = t[t0 + xc1];
    float v01 = t[t1 + xc0];
    float v11 = t[t1 + xc1];
    v00 = (bx0 && by0) ? v00 : 0.0f;
    v10 = (bx1 && by0) ? v10 : 0.0f;
    v01 = (bx0 && by1) ? v01 : 0.0f;
    v11 = (bx1 && by1) ? v11 : 0.0f;
    float acc;
    acc = __fmul_rn(v00, __fmul_rn(wx0, wy0));
    acc = __fadd_rn(acc, __fmul_rn(v10, __fmul_rn(wx1, wy0)));
    acc = __fadd_rn(acc, __fmul_rn(v01, __fmul_rn(wx0, wy1)));
    acc = __fadd_rn(acc, __fmul_rn(v11, __fmul_rn(wx1, wy1)));
    return acc;
}

// ---------------------------------------------------------------------------
// Per-patch params: CR f32 trig + flip signs + scale (one tiny block).
// ---------------------------------------------------------------------------
__global__ void pa_param_kernel(const float* __restrict__ angles,
                                const int* __restrict__ flip_h,
                                const int* __restrict__ flip_v,
                                const float* __restrict__ scales,
                                float* __restrict__ params, int N) {
    int n = blockIdx.x * blockDim.x + threadIdx.x;
    if (n >= N) return;
    double a = (double)angles[n];
    params[n * 8 + 0] = (float)cos(a);
    params[n * 8 + 1] = (float)sin(a);
    params[n * 8 + 2] = flip_h[n] ? -1.0f : 1.0f;
    params[n * 8 + 3] = flip_v[n] ? -1.0f : 1.0f;
    params[n * 8 + 4] = scales[n];
}

// ---------------------------------------------------------------------------
// Patches: one 256-thread block per (channel slice, 16-row output band).
// Pass 1 (rot+flip) computes only the needed intermediate band into LDS;
// pass 2 (scale) samples it. 10 KB LDS -> full occupancy cap.
// ---------------------------------------------------------------------------
__global__ void __launch_bounds__(256)
pa_patches(const float* __restrict__ patches,
           const float* __restrict__ params,
           float* __restrict__ out_p) {
    __shared__ float tile[TROWS * WW];      // 10 KB
    int bid = blockIdx.x;
    int band = bid & 7;                     // 8 bands per slice
    int slice = bid >> 3;                   // n*3 + ch
    int n = slice / 3;
    int tid = threadIdx.x;

    const float* pr = params + n * 8;
    float c = pr[0], s = pr[1], fsx = pr[2], fsy = pr[3], sc = pr[4];

    int r0 = band * BAND;
    // Intermediate rows needed by output rows [r0, r0+BAND): iy is monotone
    // nondecreasing in h (sc > 0), so range = [floor(iy(r0)), floor(iy(r0+15))+1].
    float iy_lo = pix_coord(__fmul_rn(sc, norm_coord(r0)));
    float iy_hi = pix_coord(__fmul_rn(sc, norm_coord(r0 + BAND - 1)));
    int lo = (int)floorf(iy_lo);
    int hi = (int)floorf(iy_hi) + 1;
    lo = lo < 0 ? 0 : lo;
    hi = hi > 127 ? 127 : hi;
    int nrows = hi - lo + 1;                // <= 19

    // pass 1: rotated rows [lo, hi] of this slice -> LDS
    const float* img = patches + (size_t)slice * HW;
    for (int p = tid; p < nrows * WW; p += 256) {
        int w = p & (WW - 1);
        int h = lo + (p >> 7);
        float x = __fmul_rn(fsx, norm_coord(w));   // exact sign flip
        float y = __fmul_rn(fsy, norm_coord(h));
        float ix = pix_coord(rot_gx(c, s, x, y));
        float iy = pix_coord(rot_gy(c, s, x, y));
        tile[p] = bilinear_g(img, ix, iy);
    }
    __syncthreads();

    // pass 2: scale-sample the band -> output rows [r0, r0+BAND)
    float* op = out_p + (size_t)slice * HW + r0 * WW;
    #pragma unroll
    for (int i = 0; i < BAND * WW / 256; ++i) {    // 8 iters
        int p = i * 256 + tid;
        int w = p & (WW - 1);
        int h = r0 + (p >> 7);
        float ix = pix_coord(__fmul_rn(sc, norm_coord(w)));
        float iy = pix_coord(__fmul_rn(sc, norm_coord(h)));
        op[p] = bilinear_band(tile, lo, ix, iy);
    }
}

// ---------------------------------------------------------------------------
// Labels: fused nearest-of-nearest index composition, no LDS.
// ---------------------------------------------------------------------------
__global__ void __launch_bounds__(256)
pa_labels(const float* __restrict__ labels,
          const float* __restrict__ params,
          float* __restrict__ out_l) {
    int idx = blockIdx.x * 256 + threadIdx.x;
    int w = idx & (WW - 1);
    int h = (idx >> 7) & (HH - 1);
    int n = idx >> 14;

    const float* pr = params + n * 8;
    float c = pr[0], s = pr[1], fsx = pr[2], fsy = pr[3], sc = pr[4];

    // pass 2 (scale) nearest index
    float ix2 = pix_coord(__fmul_rn(sc, norm_coord(w)));
    float iy2 = pix_coord(__fmul_rn(sc, norm_coord(h)));
    float xr2 = rintf(ix2), yr2 = rintf(iy2);
    float outv = 0.0f;
    if (xr2 >= 0.0f && xr2 <= 127.0f && yr2 >= 0.0f && yr2 <= 127.0f) {
        int w2 = (int)xr2, h2 = (int)yr2;
        // pass 1 (rot+flip) nearest index evaluated at (h2, w2)
        float x = __fmul_rn(fsx, norm_coord(w2));
        float y = __fmul_rn(fsy, norm_coord(h2));
        float xr1 = rintf(pix_coord(rot_gx(c, s, x, y)));
        float yr1 = rintf(pix_coord(rot_gy(c, s, x, y)));
        if (xr1 >= 0.0f && xr1 <= 127.0f && yr1 >= 0.0f && yr1 <= 127.0f) {
            outv = labels[(size_t)n * HW + (int)yr1 * WW + (int)xr1];
        }
    }
    out_l[(size_t)n * HW + h * WW + w] = outv;
}

extern "C" void kernel_launch(void* const* d_in, const int* in_sizes, int n_in,
                              void* d_out, int out_size, void* d_ws, size_t ws_size,
                              hipStream_t stream) {
    const float* patches = (const float*)d_in[0];
    const float* labels  = (const float*)d_in[1];
    const float* angles  = (const float*)d_in[2];
    const int*   flip_h  = (const int*)d_in[3];
    const int*   flip_v  = (const int*)d_in[4];
    const float* scales  = (const float*)d_in[5];

    const int N = in_sizes[2];            // B*K = 256
    float* out   = (float*)d_out;
    float* out_p = out;                   // N*3*H*W
    float* out_l = out + (size_t)N * 3 * HW;

    float* params = (float*)d_ws;         // N*8 floats

    pa_param_kernel<<<(N + 255) / 256, 256, 0, stream>>>(angles, flip_h, flip_v,
                                                         scales, params, N);
    pa_patches<<<N * 3 * 8, 256, 0, stream>>>(patches, params, out_p);
    pa_labels<<<N * HW / 256, 256, 0, stream>>>(labels, params, out_l);
}

// Round 13
// 61.013 us; speedup vs baseline: 2.1253x; 1.1631x over previous
//
#include <hip/hip_runtime.h>

// Problem constants (B=8, K=32 -> N=256 patches; C=3; H=W=128)
#define HH 128
#define WW 128
#define HW (HH * WW)
#define BAND 16            // output rows per patch block
#define TROWS 20           // LDS tile rows (max needed 19)

// ---------------------------------------------------------------------------
// Verified-correct arithmetic (R9-R12, passed):
//  - trig: correctly-rounded f32 cos/sin (f64 libm, rounded once)
//  - rotation einsum: XLA FMA lowering: gx=fma(-s,y,fl(c*x)), gy=fma(c,y,fl(s*x))
//  - scale einsum: fl(sc*x); pix chain stepwise; rintf half-even; OOB->0
//  - flip folded into pass-1 coords (exact dyadic sign flip)
//  - branchless clamped gathers: OOB corner = fl(0*w) = +0 == 0.0f, bit-same
// This round: SAME arithmetic; fused single grid (patches+labels concurrent),
// fixed-trip unrolled pass-1, hand-hoisted per-lane invariants, VGPR<=64 pin.
// ---------------------------------------------------------------------------

__device__ __forceinline__ float norm_coord(int i) {
    return __fsub_rn(__fmul_rn((float)(2 * i + 1), 0.0078125f), 1.0f);
}

__device__ __forceinline__ float pix_coord(float g) {
    float t = __fadd_rn(g, 1.0f);
    t = __fmul_rn(t, 128.0f);
    t = __fsub_rn(t, 1.0f);
    return __fmul_rn(t, 0.5f);
}

__device__ __forceinline__ int clamp127(int v) {
    return v < 0 ? 0 : (v > 127 ? 127 : v);
}

// ---------------------------------------------------------------------------
// Fused kernel. Blocks [0, NP3*8): patch (slice, band). Blocks [NP3*8, +NL):
// label chunks (4096 px each). Branch is block-uniform.
// ---------------------------------------------------------------------------
__global__ void __launch_bounds__(256, 8)
pa_fused(const float* __restrict__ patches,
         const float* __restrict__ labels,
         const float* __restrict__ params,
         float* __restrict__ out_p,
         float* __restrict__ out_l,
         int npatch_blocks) {
    __shared__ float tile[TROWS * WW];      // 10 KB
    int bid = blockIdx.x;
    int tid = threadIdx.x;

    if (bid < npatch_blocks) {
        // ----- patch path: one (channel slice, 16-row band) -----
        int band = bid & 7;
        int slice = bid >> 3;               // n*3 + ch
        int n = slice / 3;
        const float* pr = params + n * 8;
        float c = pr[0], s = pr[1], fsx = pr[2], fsy = pr[3], sc = pr[4];

        int r0 = band * BAND;
        float iy_lo = pix_coord(__fmul_rn(sc, norm_coord(r0)));
        float iy_hi = pix_coord(__fmul_rn(sc, norm_coord(r0 + BAND - 1)));
        int lo = (int)floorf(iy_lo);
        int hi = (int)floorf(iy_hi) + 1;
        lo = lo < 0 ? 0 : lo;
        hi = hi > 127 ? 127 : hi;
        int nrows = hi - lo + 1;            // <= 19

        // per-lane invariants for pass 1 (w fixed per lane)
        int w = tid & (WW - 1);
        float x1n = __fmul_rn(fsx, norm_coord(w));   // exact sign flip
        float cx = __fmul_rn(c, x1n);
        float sx = __fmul_rn(s, x1n);

        const float* img = patches + (size_t)slice * HW;
        #pragma unroll 2
        for (int i = 0; i < TROWS / 2; ++i) {        // fixed 10 iters, 2 rows/iter
            int row = i * 2 + (tid >> 7);
            if (row < nrows) {
                int h = lo + row;
                float y = __fmul_rn(fsy, norm_coord(h));
                float ix = pix_coord(__fmaf_rn(-s, y, cx));
                float iy = pix_coord(__fmaf_rn(c, y, sx));
                // branchless 4-tap gather from global
                float x0f = floorf(ix), y0f = floorf(iy);
                float wx1 = __fsub_rn(ix, x0f), wy1 = __fsub_rn(iy, y0f);
                float wx0 = __fsub_rn(1.0f, wx1), wy0 = __fsub_rn(1.0f, wy1);
                int x0 = (int)x0f, y0 = (int)y0f;
                int x1 = x0 + 1, y1 = y0 + 1;
                bool bx0 = (unsigned)x0 < 128u, bx1 = (unsigned)x1 < 128u;
                bool by0 = (unsigned)y0 < 128u, by1 = (unsigned)y1 < 128u;
                int xc0 = clamp127(x0), xc1 = clamp127(x1);
                int yc0 = clamp127(y0) * WW, yc1 = clamp127(y1) * WW;
                float v00 = img[yc0 + xc0];
                float v10 = img[yc0 + xc1];
                float v01 = img[yc1 + xc0];
                float v11 = img[yc1 + xc1];
                v00 = (bx0 && by0) ? v00 : 0.0f;
                v10 = (bx1 && by0) ? v10 : 0.0f;
                v01 = (bx0 && by1) ? v01 : 0.0f;
                v11 = (bx1 && by1) ? v11 : 0.0f;
                float acc;
                acc = __fmul_rn(v00, __fmul_rn(wx0, wy0));
                acc = __fadd_rn(acc, __fmul_rn(v10, __fmul_rn(wx1, wy0)));
                acc = __fadd_rn(acc, __fmul_rn(v01, __fmul_rn(wx0, wy1)));
                acc = __fadd_rn(acc, __fmul_rn(v11, __fmul_rn(wx1, wy1)));
                tile[row * WW + w] = acc;
            }
        }
        __syncthreads();

        // pass 2: x-side is per-lane invariant; loop only over rows
        float ix = pix_coord(__fmul_rn(sc, norm_coord(w)));
        float x0f = floorf(ix);
        float wx1 = __fsub_rn(ix, x0f);
        float wx0 = __fsub_rn(1.0f, wx1);
        int x0 = (int)x0f, x1 = x0 + 1;
        bool bx0 = (unsigned)x0 < 128u, bx1 = (unsigned)x1 < 128u;
        int xc0 = clamp127(x0), xc1 = clamp127(x1);

        float* op = out_p + (size_t)slice * HW + r0 * WW;
        #pragma unroll 4
        for (int i = 0; i < BAND / 2; ++i) {         // 8 iters, 2 rows/iter
            int row = i * 2 + (tid >> 7);
            int h = r0 + row;
            float iy = pix_coord(__fmul_rn(sc, norm_coord(h)));
            float y0f = floorf(iy);
            float wy1 = __fsub_rn(iy, y0f);
            float wy0 = __fsub_rn(1.0f, wy1);
            int y0 = (int)y0f, y1 = y0 + 1;
            bool by0 = (unsigned)y0 < 128u, by1 = (unsigned)y1 < 128u;
            int t0 = (clamp127(y0) - lo) * WW, t1 = (clamp127(y1) - lo) * WW;
            float v00 = tile[t0 + xc0];
            float v10 = tile[t0 + xc1];
            float v01 = tile[t1 + xc0];
            float v11 = tile[t1 + xc1];
            v00 = (bx0 && by0) ? v00 : 0.0f;
            v10 = (bx1 && by0) ? v10 : 0.0f;
            v01 = (bx0 && by1) ? v01 : 0.0f;
            v11 = (bx1 && by1) ? v11 : 0.0f;
            float acc;
            acc = __fmul_rn(v00, __fmul_rn(wx0, wy0));
            acc = __fadd_rn(acc, __fmul_rn(v10, __fmul_rn(wx1, wy0)));
            acc = __fadd_rn(acc, __fmul_rn(v01, __fmul_rn(wx0, wy1)));
            acc = __fadd_rn(acc, __fmul_rn(v11, __fmul_rn(wx1, wy1)));
            op[row * WW + w] = acc;
        }
    } else {
        // ----- label path: fused nearest-of-nearest, 4096 px per block -----
        int lb = bid - npatch_blocks;
        int n = lb >> 2;                     // 4 chunks per label slice
        const float* pr = params + n * 8;
        float c = pr[0], s = pr[1], fsx = pr[2], fsy = pr[3], sc = pr[4];
        const float* lab = labels + (size_t)n * HW;
        float* ol = out_l + (size_t)n * HW;

        int base = (lb & 3) * 4096;          // pixel offset within slice
        int w = tid & (WW - 1);
        // pass-2 x-index per lane invariant
        float ix2 = pix_coord(__fmul_rn(sc, norm_coord(w)));
        float xr2 = rintf(ix2);
        bool okx2 = (xr2 >= 0.0f) && (xr2 <= 127.0f);
        int w2 = (int)xr2;
        float xw2 = okx2 ? __fmul_rn(fsx, norm_coord(w2)) : 0.0f;

        #pragma unroll 4
        for (int i = 0; i < 16; ++i) {
            int p = base + i * 256 + tid;
            int h = (p >> 7) & (HH - 1);
            float iy2 = pix_coord(__fmul_rn(sc, norm_coord(h)));
            float yr2 = rintf(iy2);
            float outv = 0.0f;
            if (okx2 && yr2 >= 0.0f && yr2 <= 127.0f) {
                int h2 = (int)yr2;
                float y = __fmul_rn(fsy, norm_coord(h2));
                float cx = __fmul_rn(c, xw2);
                float sx = __fmul_rn(s, xw2);
                float xr1 = rintf(pix_coord(__fmaf_rn(-s, y, cx)));
                float yr1 = rintf(pix_coord(__fmaf_rn(c, y, sx)));
                if (xr1 >= 0.0f && xr1 <= 127.0f &&
                    yr1 >= 0.0f && yr1 <= 127.0f) {
                    outv = lab[(int)yr1 * WW + (int)xr1];
                }
            }
            ol[p] = outv;
        }
    }
}

// ---------------------------------------------------------------------------
// Per-patch params: CR f32 trig + flip signs + scale.
// ---------------------------------------------------------------------------
__global__ void pa_param_kernel(const float* __restrict__ angles,
                                const int* __restrict__ flip_h,
                                const int* __restrict__ flip_v,
                                const float* __restrict__ scales,
                                float* __restrict__ params, int N) {
    int n = blockIdx.x * blockDim.x + threadIdx.x;
    if (n >= N) return;
    double a = (double)angles[n];
    params[n * 8 + 0] = (float)cos(a);
    params[n * 8 + 1] = (float)sin(a);
    params[n * 8 + 2] = flip_h[n] ? -1.0f : 1.0f;
    params[n * 8 + 3] = flip_v[n] ? -1.0f : 1.0f;
    params[n * 8 + 4] = scales[n];
}

extern "C" void kernel_launch(void* const* d_in, const int* in_sizes, int n_in,
                              void* d_out, int out_size, void* d_ws, size_t ws_size,
                              hipStream_t stream) {
    const float* patches = (const float*)d_in[0];
    const float* labels  = (const float*)d_in[1];
    const float* angles  = (const float*)d_in[2];
    const int*   flip_h  = (const int*)d_in[3];
    const int*   flip_v  = (const int*)d_in[4];
    const float* scales  = (const float*)d_in[5];

    const int N = in_sizes[2];            // B*K = 256
    float* out   = (float*)d_out;
    float* out_p = out;                   // N*3*H*W
    float* out_l = out + (size_t)N * 3 * HW;

    float* params = (float*)d_ws;         // N*8 floats

    pa_param_kernel<<<(N + 255) / 256, 256, 0, stream>>>(angles, flip_h, flip_v,
                                                         scales, params, N);
    int npatch_blocks = N * 3 * 8;        // 6144
    int nlabel_blocks = N * 4;            // 1024 (4096 px each)
    pa_fused<<<npatch_blocks + nlabel_blocks, 256, 0, stream>>>(
        patches, labels, params, out_p, out_l, npatch_blocks);
}

// Round 14
// 59.363 us; speedup vs baseline: 2.1844x; 1.0278x over previous
//
#include <hip/hip_runtime.h>

// Problem constants (B=8, K=32 -> N=256 patches; C=3; H=W=128)
#define HH 128
#define WW 128
#define HW (HH * WW)
#define BAND 8             // output rows per patch block
#define TROWS 10           // LDS tile rows: span = 7*sc < 7.7 -> <=10 rows

// ---------------------------------------------------------------------------
// Verified-correct arithmetic (R9-R13, passed):
//  - trig: correctly-rounded f32 cos/sin (f64 libm, rounded once)
//  - rotation einsum: XLA FMA lowering: gx=fma(-s,y,fl(c*x)), gy=fma(c,y,fl(s*x))
//  - scale einsum: fl(sc*x); pix chain stepwise; rintf half-even; OOB->0
//  - flip folded into pass-1 coords (exact dyadic sign flip)
//  - branchless clamped gathers: OOB corner = fl(0*w) = +0 == 0.0f, bit-same
// This round: SAME arithmetic; 3 channels per block (coordinate math computed
// once, reused 3x), per-block params (single dispatch, no workspace).
// ---------------------------------------------------------------------------

__device__ __forceinline__ float norm_coord(int i) {
    return __fsub_rn(__fmul_rn((float)(2 * i + 1), 0.0078125f), 1.0f);
}

__device__ __forceinline__ float pix_coord(float g) {
    float t = __fadd_rn(g, 1.0f);
    t = __fmul_rn(t, 128.0f);
    t = __fsub_rn(t, 1.0f);
    return __fmul_rn(t, 0.5f);
}

__device__ __forceinline__ int clamp127(int v) {
    return v < 0 ? 0 : (v > 127 ? 127 : v);
}

// ---------------------------------------------------------------------------
// Single fused kernel. Blocks [0, NP): patch (n, 8-row band) - all 3 channels.
// Blocks [NP, NP+NL): label chunks (4096 px each). Branch is block-uniform.
// ---------------------------------------------------------------------------
__global__ void __launch_bounds__(256, 8)
pa_all(const float* __restrict__ patches,
       const float* __restrict__ labels,
       const float* __restrict__ angles,
       const int* __restrict__ flip_h,
       const int* __restrict__ flip_v,
       const float* __restrict__ scales,
       float* __restrict__ out_p,
       float* __restrict__ out_l,
       int npatch_blocks) {
    __shared__ float tile[3][TROWS * WW];   // 15 KB
    __shared__ float prm[5];
    int bid = blockIdx.x;
    int tid = threadIdx.x;
    bool is_patch = bid < npatch_blocks;
    int n = is_patch ? (bid >> 4) : ((bid - npatch_blocks) >> 2);

    if (tid == 0) {
        double a = (double)angles[n];
        prm[0] = (float)cos(a);             // correctly-rounded f32
        prm[1] = (float)sin(a);
        prm[2] = flip_h[n] ? -1.0f : 1.0f;
        prm[3] = flip_v[n] ? -1.0f : 1.0f;
        prm[4] = scales[n];
    }
    __syncthreads();
    float c = prm[0], s = prm[1], fsx = prm[2], fsy = prm[3], sc = prm[4];

    if (is_patch) {
        // ----- patch path: (n, band) covers 3 channels x 8 rows -----
        int band = bid & 15;
        int r0 = band * BAND;
        float iy_lo = pix_coord(__fmul_rn(sc, norm_coord(r0)));
        float iy_hi = pix_coord(__fmul_rn(sc, norm_coord(r0 + BAND - 1)));
        int lo = (int)floorf(iy_lo);
        int hi = (int)floorf(iy_hi) + 1;
        lo = lo < 0 ? 0 : lo;
        hi = hi > 127 ? 127 : hi;
        int nrows = hi - lo + 1;            // <= 10

        int w = tid & (WW - 1);
        // per-lane pass-1 invariants (w fixed per lane)
        float x1n = __fmul_rn(fsx, norm_coord(w));   // exact sign flip
        float cx = __fmul_rn(c, x1n);
        float sx = __fmul_rn(s, x1n);

        const float* img = patches + (size_t)n * 3 * HW;
        #pragma unroll
        for (int i = 0; i < TROWS / 2; ++i) {        // 5 iters (wave-uniform rows)
            int row = i * 2 + (tid >> 7);
            if (row < nrows) {
                int h = lo + row;
                float y = __fmul_rn(fsy, norm_coord(h));
                float ix = pix_coord(__fmaf_rn(-s, y, cx));
                float iy = pix_coord(__fmaf_rn(c, y, sx));
                float x0f = floorf(ix), y0f = floorf(iy);
                float wx1 = __fsub_rn(ix, x0f), wy1 = __fsub_rn(iy, y0f);
                float wx0 = __fsub_rn(1.0f, wx1), wy0 = __fsub_rn(1.0f, wy1);
                float w00 = __fmul_rn(wx0, wy0), w10 = __fmul_rn(wx1, wy0);
                float w01 = __fmul_rn(wx0, wy1), w11 = __fmul_rn(wx1, wy1);
                int x0 = (int)x0f, y0 = (int)y0f;
                int x1 = x0 + 1, y1 = y0 + 1;
                bool bx0 = (unsigned)x0 < 128u, bx1 = (unsigned)x1 < 128u;
                bool by0 = (unsigned)y0 < 128u, by1 = (unsigned)y1 < 128u;
                bool b00 = bx0 && by0, b10 = bx1 && by0;
                bool b01 = bx0 && by1, b11 = bx1 && by1;
                int xc0 = clamp127(x0), xc1 = clamp127(x1);
                int yc0 = clamp127(y0) * WW, yc1 = clamp127(y1) * WW;
                int o00 = yc0 + xc0, o10 = yc0 + xc1;
                int o01 = yc1 + xc0, o11 = yc1 + xc1;
                #pragma unroll
                for (int ch = 0; ch < 3; ++ch) {
                    const float* im = img + ch * HW;
                    float v00 = im[o00];
                    float v10 = im[o10];
                    float v01 = im[o01];
                    float v11 = im[o11];
                    v00 = b00 ? v00 : 0.0f;
                    v10 = b10 ? v10 : 0.0f;
                    v01 = b01 ? v01 : 0.0f;
                    v11 = b11 ? v11 : 0.0f;
                    float acc;
                    acc = __fmul_rn(v00, w00);
                    acc = __fadd_rn(acc, __fmul_rn(v10, w10));
                    acc = __fadd_rn(acc, __fmul_rn(v01, w01));
                    acc = __fadd_rn(acc, __fmul_rn(v11, w11));
                    tile[ch][row * WW + w] = acc;
                }
            }
        }
        __syncthreads();

        // pass 2: x-side per-lane invariant
        float ix = pix_coord(__fmul_rn(sc, norm_coord(w)));
        float x0f = floorf(ix);
        float wx1 = __fsub_rn(ix, x0f);
        float wx0 = __fsub_rn(1.0f, wx1);
        int x0 = (int)x0f, x1 = x0 + 1;
        bool bx0 = (unsigned)x0 < 128u, bx1 = (unsigned)x1 < 128u;
        int xc0 = clamp127(x0), xc1 = clamp127(x1);

        float* op = out_p + (size_t)n * 3 * HW + r0 * WW;
        #pragma unroll
        for (int i = 0; i < BAND / 2; ++i) {         // 4 iters
            int row = i * 2 + (tid >> 7);
            int h = r0 + row;
            float iy = pix_coord(__fmul_rn(sc, norm_coord(h)));
            float y0f = floorf(iy);
            float wy1 = __fsub_rn(iy, y0f);
            float wy0 = __fsub_rn(1.0f, wy1);
            float w00 = __fmul_rn(wx0, wy0), w10 = __fmul_rn(wx1, wy0);
            float w01 = __fmul_rn(wx0, wy1), w11 = __fmul_rn(wx1, wy1);
            int y0 = (int)y0f, y1 = y0 + 1;
            bool by0 = (unsigned)y0 < 128u, by1 = (unsigned)y1 < 128u;
            bool b00 = bx0 && by0, b10 = bx1 && by0;
            bool b01 = bx0 && by1, b11 = bx1 && by1;
            int t0 = (clamp127(y0) - lo) * WW, t1 = (clamp127(y1) - lo) * WW;
            #pragma unroll
            for (int ch = 0; ch < 3; ++ch) {
                float v00 = tile[ch][t0 + xc0];
                float v10 = tile[ch][t0 + xc1];
                float v01 = tile[ch][t1 + xc0];
                float v11 = tile[ch][t1 + xc1];
                v00 = b00 ? v00 : 0.0f;
                v10 = b10 ? v10 : 0.0f;
                v01 = b01 ? v01 : 0.0f;
                v11 = b11 ? v11 : 0.0f;
                float acc;
                acc = __fmul_rn(v00, w00);
                acc = __fadd_rn(acc, __fmul_rn(v10, w10));
                acc = __fadd_rn(acc, __fmul_rn(v01, w01));
                acc = __fadd_rn(acc, __fmul_rn(v11, w11));
                op[ch * HW + row * WW + w] = acc;
            }
        }
    } else {
        // ----- label path: fused nearest-of-nearest, 4096 px per block -----
        int lb = bid - npatch_blocks;
        const float* lab = labels + (size_t)n * HW;
        float* ol = out_l + (size_t)n * HW;

        int base = (lb & 3) * 4096;
        int w = tid & (WW - 1);
        float ix2 = pix_coord(__fmul_rn(sc, norm_coord(w)));
        float xr2 = rintf(ix2);
        bool okx2 = (xr2 >= 0.0f) && (xr2 <= 127.0f);
        int w2 = (int)xr2;
        float xw2 = okx2 ? __fmul_rn(fsx, norm_coord(w2)) : 0.0f;
        float cx = __fmul_rn(c, xw2);
        float sx = __fmul_rn(s, xw2);

        #pragma unroll 4
        for (int i = 0; i < 16; ++i) {
            int p = base + i * 256 + tid;
            int h = (p >> 7) & (HH - 1);
            float iy2 = pix_coord(__fmul_rn(sc, norm_coord(h)));
            float yr2 = rintf(iy2);
            float outv = 0.0f;
            if (okx2 && yr2 >= 0.0f && yr2 <= 127.0f) {
                int h2 = (int)yr2;
                float y = __fmul_rn(fsy, norm_coord(h2));
                float xr1 = rintf(pix_coord(__fmaf_rn(-s, y, cx)));
                float yr1 = rintf(pix_coord(__fmaf_rn(c, y, sx)));
                if (xr1 >= 0.0f && xr1 <= 127.0f &&
                    yr1 >= 0.0f && yr1 <= 127.0f) {
                    outv = lab[(int)yr1 * WW + (int)xr1];
                }
            }
            ol[p] = outv;
        }
    }
}

extern "C" void kernel_launch(void* const* d_in, const int* in_sizes, int n_in,
                              void* d_out, int out_size, void* d_ws, size_t ws_size,
                              hipStream_t stream) {
    const float* patches = (const float*)d_in[0];
    const float* labels  = (const float*)d_in[1];
    const float* angles  = (const float*)d_in[2];
    const int*   flip_h  = (const int*)d_in[3];
    const int*   flip_v  = (const int*)d_in[4];
    const float* scales  = (const float*)d_in[5];

    const int N = in_sizes[2];            // B*K = 256
    float* out   = (float*)d_out;
    float* out_p = out;                   // N*3*H*W
    float* out_l = out + (size_t)N * 3 * HW;

    int npatch_blocks = N * 16;           // 4096: (n, 8-row band), 3 ch each
    int nlabel_blocks = N * 4;            // 1024: 4096 px each
    pa_all<<<npatch_blocks + nlabel_blocks, 256, 0, stream>>>(
        patches, labels, angles, flip_h, flip_v, scales,
        out_p, out_l, npatch_blocks);
}